// Round 6
// baseline (743.887 us; speedup 1.0000x reference)
//
#include <hip/hip_runtime.h>
#include <hip/hip_bf16.h>
#include <math.h>

#define D_IN   768
#define D_SAE  12288
#define T_LEN  64
#define K_TOP  64
#define B_SZ   32
#define NROWS  (B_SZ * T_LEN)   // 2048
#define KT     24               // 768/32 k-tiles

typedef _Float16 h8 __attribute__((ext_vector_type(8)));
typedef float f4 __attribute__((ext_vector_type(4)));

// ---------- helpers ----------
__device__ __forceinline__ unsigned int f2key(float f) {
  unsigned int u = __float_as_uint(f);
  return (u & 0x80000000u) ? ~u : (u | 0x80000000u);
}

// raw barrier: order LDS ops, do NOT drain vmcnt (keep global loads/stores in flight)
__device__ __forceinline__ void barL() {
  __builtin_amdgcn_sched_barrier(0);
  asm volatile("s_waitcnt lgkmcnt(0)" ::: "memory");
  __builtin_amdgcn_s_barrier();
  __builtin_amdgcn_sched_barrier(0);
}

#define GLOAD16(g, l)                                                        \
  __builtin_amdgcn_global_load_lds(                                          \
      (const __attribute__((address_space(1))) unsigned int*)(g),            \
      (__attribute__((address_space(3))) unsigned int*)(l), 16, 0, 0)

// ---------- kernel 0: init output (loss slot + z_last region) ----------
__global__ void sae_init_out(float* __restrict__ d_out) {
  int i = blockIdx.x * blockDim.x + threadIdx.x;
  if (i == 0) d_out[0] = 0.0f;
  if (i < B_SZ * D_SAE) d_out[1 + (size_t)NROWS * D_IN + i] = 0.0f;
}

// ---------- split kernels: fp32 -> (hi, lo*4096) fp16, MFMA-fragment packed ----------
__global__ __launch_bounds__(256) void sae_split_A(
    const float* __restrict__ A, _Float16* __restrict__ Ah, _Float16* __restrict__ Al) {
  int g = blockIdx.x * 256 + threadIdx.x;          // < 128*24*64 = 196608
  int tile = g >> 6, l = g & 63;
  int tm = tile / KT, tk = tile - tm * KT;
  int m = (tm << 4) + (l & 15);
  int k = (tk << 5) + ((l >> 4) << 3);
  const float* src = A + (size_t)m * D_IN + k;
  float4 v0 = *(const float4*)src;
  float4 v1 = *(const float4*)(src + 4);
  float f[8] = {v0.x, v0.y, v0.z, v0.w, v1.x, v1.y, v1.z, v1.w};
  h8 hi, lo;
#pragma unroll
  for (int j = 0; j < 8; ++j) {
    _Float16 h = (_Float16)f[j];
    hi[j] = h;
    lo[j] = (_Float16)((f[j] - (float)h) * 4096.0f);
  }
  *(h8*)(Ah + (size_t)g * 8) = hi;
  *(h8*)(Al + (size_t)g * 8) = lo;
}

__global__ __launch_bounds__(256) void sae_split_B(
    const float* __restrict__ B, _Float16* __restrict__ Bh, _Float16* __restrict__ Bl) {
  int g = blockIdx.x * 256 + threadIdx.x;          // < 768*24*64 = 1179648
  int tile = g >> 6, l = g & 63;
  int tn = tile / KT, tk = tile - tn * KT;
  int n = (tn << 4) + (l & 15);
  int k = (tk << 5) + ((l >> 4) << 3);
  h8 hi, lo;
#pragma unroll
  for (int j = 0; j < 8; ++j) {
    float f = B[(size_t)(k + j) * D_SAE + n];
    _Float16 h = (_Float16)f;
    hi[j] = h;
    lo[j] = (_Float16)((f - (float)h) * 4096.0f);
  }
  *(h8*)(Bh + (size_t)g * 8) = hi;
  *(h8*)(Bl + (size_t)g * 8) = lo;
}

// ---------- kernel 1: encoder GEMM via fp16-split MFMA ----------
__global__ __launch_bounds__(512) void sae_gemm_mfma(
    const _Float16* __restrict__ Ah, const _Float16* __restrict__ Al,
    const _Float16* __restrict__ Bh, const _Float16* __restrict__ Bl,
    const float* __restrict__ bias, float* __restrict__ C) {
  __shared__ _Float16 lds[2][16384];               // 2 x 32 KB
  const int tid = threadIdx.x;
  const int w = tid >> 6, lane = tid & 63;
  const int wm = w >> 2, wn = w & 3;
  const int bmT = blockIdx.y * 8;
  const int bnT = blockIdx.x * 8;

  f4 accm[4][2], accc[4][2];
#pragma unroll
  for (int i = 0; i < 4; ++i)
#pragma unroll
    for (int j = 0; j < 2; ++j) {
      accm[i][j] = (f4){0.f, 0.f, 0.f, 0.f};
      accc[i][j] = (f4){0.f, 0.f, 0.f, 0.f};
    }

#define STAGE(buf, tk)                                                         \
  {                                                                            \
    const _Float16* s0 = Ah + ((size_t)(bmT + w) * KT + (tk)) * 512;           \
    const _Float16* s1 = Al + ((size_t)(bmT + w) * KT + (tk)) * 512;           \
    const _Float16* s2 = Bh + ((size_t)(bnT + w) * KT + (tk)) * 512;           \
    const _Float16* s3 = Bl + ((size_t)(bnT + w) * KT + (tk)) * 512;           \
    GLOAD16(s0 + lane * 8, &lds[buf][(0 * 8 + w) * 512]);                      \
    GLOAD16(s1 + lane * 8, &lds[buf][(1 * 8 + w) * 512]);                      \
    GLOAD16(s2 + lane * 8, &lds[buf][(2 * 8 + w) * 512]);                      \
    GLOAD16(s3 + lane * 8, &lds[buf][(3 * 8 + w) * 512]);                      \
  }

  STAGE(0, 0);
  __syncthreads();
  for (int tk = 0; tk < KT; ++tk) {
    int buf = tk & 1;
    if (tk + 1 < KT) STAGE(buf ^ 1, tk + 1);
    h8 ah[4], al4[4], bh2[2], bl2[2];
#pragma unroll
    for (int i = 0; i < 4; ++i) {
      ah[i]  = *(const h8*)&lds[buf][(wm * 4 + i) * 512 + lane * 8];
      al4[i] = *(const h8*)&lds[buf][4096 + (wm * 4 + i) * 512 + lane * 8];
    }
#pragma unroll
    for (int j = 0; j < 2; ++j) {
      bh2[j] = *(const h8*)&lds[buf][8192 + (wn * 2 + j) * 512 + lane * 8];
      bl2[j] = *(const h8*)&lds[buf][12288 + (wn * 2 + j) * 512 + lane * 8];
    }
#pragma unroll
    for (int i = 0; i < 4; ++i)
#pragma unroll
      for (int j = 0; j < 2; ++j) {
        accm[i][j] = __builtin_amdgcn_mfma_f32_16x16x32_f16(ah[i], bh2[j], accm[i][j], 0, 0, 0);
        accc[i][j] = __builtin_amdgcn_mfma_f32_16x16x32_f16(ah[i], bl2[j], accc[i][j], 0, 0, 0);
        accc[i][j] = __builtin_amdgcn_mfma_f32_16x16x32_f16(al4[i], bh2[j], accc[i][j], 0, 0, 0);
      }
    __syncthreads();
  }
#undef STAGE

  const float kLo = 1.0f / 4096.0f;
  const int colb = blockIdx.x * 128 + wn * 32;
  const int rowb = blockIdx.y * 128 + wm * 64;
#pragma unroll
  for (int j = 0; j < 2; ++j) {
    int col = colb + j * 16 + (lane & 15);
    float bv = bias[col];
#pragma unroll
    for (int i = 0; i < 4; ++i) {
      int row = rowb + i * 16 + ((lane >> 4) << 2);
#pragma unroll
      for (int r = 0; r < 4; ++r)
        C[(size_t)(row + r) * D_SAE + col] = accm[i][j][r] + accc[i][j][r] * kLo + bv;
    }
  }
}

// ---------- kernel 2: exact top-128 per row (radix select) ----------
__global__ __launch_bounds__(256) void sae_top128(
    const float* __restrict__ pre, int* __restrict__ t128i, float* __restrict__ t128v) {
  const int row = blockIdx.x;
  const int tid = threadIdx.x;
  __shared__ unsigned int keys[D_SAE];
  __shared__ int hist[256];
  __shared__ int scn[256];
  __shared__ int sb, srem, scnt, scnt2;
  const float* p = pre + (size_t)row * D_SAE;
  for (int i = tid; i < D_SAE; i += 256) keys[i] = f2key(p[i]);

  const unsigned int PMASK[4] = {0u, 0xFF000000u, 0xFFFF0000u, 0xFFFFFF00u};
  unsigned int pacc = 0;
  int remaining = 128;

  for (int round = 0; round < 4; ++round) {
    const int shift = 24 - 8 * round;
    hist[tid] = 0;
    __syncthreads();
    unsigned int pm = PMASK[round];
    for (int i = tid; i < D_SAE; i += 256) {
      unsigned int k = keys[i];
      if ((k & pm) == pacc) atomicAdd(&hist[(k >> shift) & 255], 1);
    }
    __syncthreads();
    scn[tid] = hist[tid];
    __syncthreads();
    for (int d = 1; d < 256; d <<= 1) {
      int nv = scn[tid] + ((tid + d < 256) ? scn[tid + d] : 0);
      __syncthreads();
      scn[tid] = nv;
      __syncthreads();
    }
    int cum = scn[tid];
    int nxt = (tid < 255) ? scn[tid + 1] : 0;
    if (cum >= remaining && nxt < remaining) { sb = tid; srem = remaining - nxt; }
    __syncthreads();
    pacc |= ((unsigned int)sb) << shift;
    remaining = srem;
    __syncthreads();
  }
  if (tid == 0) { scnt = 0; scnt2 = 0; }
  __syncthreads();
  const int ngt = 128 - remaining;
  for (int i = tid; i < D_SAE; i += 256) {
    unsigned int k = keys[i];
    if (k > pacc) {
      int pos = atomicAdd(&scnt, 1);
      t128i[row * 128 + pos] = i;
      t128v[row * 128 + pos] = p[i];
    } else if (k == pacc) {
      int pos = atomicAdd(&scnt2, 1);
      if (pos < remaining) {
        t128i[row * 128 + ngt + pos] = i;
        t128v[row * 128 + ngt + pos] = p[i];
      }
    }
  }
}

// ---------- kernel 3: recurrence — 4 waves, rank-as-position, DMA row buffer ----------
// waves 0-2: 192 candidate threads. wave 3: DMA-stages next pre row (48 KB) into
// LDS via global_load_lds + clears boost; drains its own vmcnt in phase D.
// 4 raw (lgkmcnt-only) barriers per step.
__global__ __launch_bounds__(256) void sae_recur(
    const float* __restrict__ pre, const int* __restrict__ t128i,
    const float* __restrict__ t128v, const float* __restrict__ gate_raw,
    int* __restrict__ zi, float* __restrict__ zv) {
  const int b = blockIdx.x;
  const int tid = threadIdx.x;
  const int lane = tid & 63;
  const int w = tid >> 6;
  __shared__ float prerow[D_SAE];                     // 48 KB (row t, then t+1)
  __shared__ float boost[D_SAE];                      // 48 KB
  __shared__ float sgate[D_SAE];                      // 48 KB
  __shared__ unsigned char mark[D_SAE];               // 12 KB
  __shared__ __align__(16) unsigned long long ckey[192];
  __shared__ int   szi[64];
  __shared__ float szv[64];
  __shared__ float szg[64];                           // z * sigmoid(gate) per slot

  for (int i = tid; i < D_SAE; i += 256) {
    boost[i] = 0.0f;
    mark[i] = 0xFFu;
    sgate[i] = 1.0f / (1.0f + __expf(-gate_raw[i]));
  }
  if (tid < 64) { szi[tid] = tid; szv[tid] = 0.0f; szg[tid] = 0.0f; }
  // stage row 0 (full 12288 floats: 3072 float4 over 256 threads, 12 iters)
  {
    const float4* src = (const float4*)(pre + (size_t)(b * T_LEN) * D_SAE);
#pragma unroll
    for (int i = 0; i < 12; ++i) {
      float4 v = src[i * 256 + tid];
      *(float4*)&prerow[(size_t)(i * 256 + tid) * 4] = v;
    }
  }
  int ri = 0; float rv = 0.0f;
  if (tid < 128) {
    ri = t128i[(size_t)(b * T_LEN) * 128 + tid];
    rv = t128v[(size_t)(b * T_LEN) * 128 + tid];
  }
  __syncthreads();

  const unsigned long long lt64 = (1ull << lane) - 1ull;
  int zidx = 0; float zval = 0.0f, gz = 0.0f, pv = 0.0f;

  for (int t = 0; t < T_LEN; ++t) {
    const int row = b * T_LEN + t;
    // ---- A: load state; scatter boost; mark current top-128 ----
    if (w == 0) {
      zidx = szi[lane]; zval = szv[lane]; gz = szg[lane];
      if (zval > 0.0f) boost[zidx] = gz;
      pv = prerow[zidx];
    }
    if (tid < 128) mark[ri] = (unsigned char)t;
    barL();
    // ---- B: boost gather + key build; wave0 handles extras/pads ----
    unsigned long long kc = 0;
    float myv = 0.0f; int myi = 0;
    if (tid < 128) {
      myi = ri;
      myv = rv + boost[ri];
      kc = (((unsigned long long)f2key(myv)) << 14) | (unsigned)(16383 - myi);
      ckey[tid] = kc;
    }
    if (w == 0) {
      bool active = (zval > 0.0f);
      bool matched = active && (mark[zidx] == (unsigned char)t);
      bool extra = active && !matched;
      unsigned long long em = __ballot(extra);
      int ne = __popcll(em);
      if (extra) {
        int pos = __popcll(em & lt64);
        float v = pv + gz;
        ckey[128 + pos] =
            (((unsigned long long)f2key(v)) << 14) | (unsigned)(16383 - zidx);
      }
      if (lane >= ne) {
        ckey[128 + lane] = (((unsigned long long)f2key(-INFINITY)) << 14) |
                           (unsigned)(16383 - (D_SAE + lane));
      }
    }
    barL();
    // ---- C: t128 prefetch + full-row DMA stage (wave3) + counting rank ----
    int nri = ri; float nrv = rv;
    if (tid < 128 && t + 1 < T_LEN) {
      nri = t128i[(size_t)(row + 1) * 128 + tid];
      nrv = t128v[(size_t)(row + 1) * 128 + tid];
    }
    if (w == 3) {
      if (t + 1 < T_LEN) {
        // 48 KB row = 48 chunks of (64 lanes x 16 B); DMA direct global->LDS
        const float* src = pre + (size_t)(row + 1) * D_SAE + lane * 4;
#pragma unroll
        for (int i = 0; i < 48; ++i)
          GLOAD16(src + i * 256, &prerow[i * 256]);
      }
      int oz = szi[lane];
      boost[oz] = 0.0f;                       // clear old state while DMA flies
    }
    if (tid >= 128 && tid < 192) {
      kc = ckey[tid];
      myi = 16383 - (int)(kc & 0x3FFFu);
      unsigned int hv = (unsigned int)(kc >> 14);
      myv = (hv & 0x80000000u) ? __uint_as_float(hv & 0x7FFFFFFFu)
                               : __uint_as_float(~hv);
    }
    int r = 0;
    if (tid < 192) {
#pragma unroll 8
      for (int j = 0; j < 96; ++j) {
        ulonglong2 kk = *(const ulonglong2*)&ckey[2 * j];
        r += (int)(kk.x > kc) + (int)(kk.y > kc);
      }
    }
    barL();
    // ---- D: rank IS the position (ranks of selected = {0..63}) ----
    if (tid < 192 && r < K_TOP) {
      float rl = fmaxf(myv, 0.0f);
      szi[r] = myi;
      szv[r] = rl;
      szg[r] = (rl > 0.0f) ? rl * sgate[myi] : 0.0f;
      zi[(size_t)row * 64 + r] = myi;      // fire-and-forget global stores
      zv[(size_t)row * 64 + r] = rl;
    }
    if (w == 3) {
      // wave 3 drains its row-DMA so prerow is complete before next phase A
      asm volatile("s_waitcnt vmcnt(0)" ::: "memory");
    }
    barL();
    ri = nri; rv = nrv;
  }
}

// ---------- kernel 4: sparse decoder + recon loss ----------
__global__ __launch_bounds__(256) void sae_decode(
    const float* __restrict__ x, const float* __restrict__ W_dec,
    const float* __restrict__ b_dec, const int* __restrict__ zi,
    const float* __restrict__ zv, float* __restrict__ d_out) {
  const int row = blockIdx.x;
  const int tid = threadIdx.x;
  __shared__ int   si[64];
  __shared__ float sv[64];
  __shared__ float red[4];
  if (tid < 64) { si[tid] = zi[row * 64 + tid]; sv[tid] = zv[row * 64 + tid]; }
  __syncthreads();
  float a0 = b_dec[tid], a1 = b_dec[tid + 256], a2 = b_dec[tid + 512];
  for (int k = 0; k < 64; ++k) {
    float v = sv[k];
    if (v != 0.0f) {
      const float* wp = W_dec + (size_t)si[k] * D_IN;
      a0 = fmaf(v, wp[tid], a0);
      a1 = fmaf(v, wp[tid + 256], a1);
      a2 = fmaf(v, wp[tid + 512], a2);
    }
  }
  float* xhat = d_out + 1;
  size_t base = (size_t)row * D_IN;
  xhat[base + tid]       = a0;
  xhat[base + tid + 256] = a1;
  xhat[base + tid + 512] = a2;
  float d0 = a0 - x[base + tid];
  float d1 = a1 - x[base + tid + 256];
  float d2 = a2 - x[base + tid + 512];
  float s = d0 * d0 + d1 * d1 + d2 * d2;
  for (int o = 32; o > 0; o >>= 1) s += __shfl_down(s, o);
  if ((tid & 63) == 0) red[tid >> 6] = s;
  __syncthreads();
  if (tid == 0) {
    float tot = red[0] + red[1] + red[2] + red[3];
    atomicAdd(d_out, tot * (1.0f / (float)NROWS));
  }
}

// ---------- kernel 5: scatter z at t = T-1 ----------
__global__ void sae_scatter_last(const int* __restrict__ zi,
                                 const float* __restrict__ zv,
                                 float* __restrict__ d_out) {
  int i = blockIdx.x * blockDim.x + threadIdx.x;
  if (i >= B_SZ * 64) return;
  int b = i >> 6, k = i & 63;
  int row = b * T_LEN + (T_LEN - 1);
  float* zlast = d_out + 1 + (size_t)NROWS * D_IN;
  zlast[(size_t)b * D_SAE + zi[row * 64 + k]] = zv[row * 64 + k];
}

// ---------- launch ----------
extern "C" void kernel_launch(void* const* d_in, const int* in_sizes, int n_in,
                              void* d_out, int out_size, void* d_ws, size_t ws_size,
                              hipStream_t stream) {
  const float* x        = (const float*)d_in[0];
  const float* W_enc    = (const float*)d_in[1];
  const float* W_dec    = (const float*)d_in[2];
  const float* b_enc    = (const float*)d_in[3];
  const float* b_dec    = (const float*)d_in[4];
  const float* gate_raw = (const float*)d_in[5];
  float* out = (float*)d_out;

  char* ws = (char*)d_ws;
  size_t off = 0;
  float* pre   = (float*)(ws + off); off += (size_t)NROWS * D_SAE * sizeof(float);
  int*   t128i = (int*)(ws + off);   off += (size_t)NROWS * 128 * sizeof(int);
  float* t128v = (float*)(ws + off); off += (size_t)NROWS * 128 * sizeof(float);
  int*   zidx  = (int*)(ws + off);   off += (size_t)NROWS * 64 * sizeof(int);
  float* zval  = (float*)(ws + off); off += (size_t)NROWS * 64 * sizeof(float);
  _Float16* Ah = (_Float16*)(ws + off); off += (size_t)NROWS * D_IN * sizeof(_Float16);
  _Float16* Al = (_Float16*)(ws + off); off += (size_t)NROWS * D_IN * sizeof(_Float16);
  _Float16* Bh = (_Float16*)(ws + off); off += (size_t)D_IN * D_SAE * sizeof(_Float16);
  _Float16* Bl = (_Float16*)(ws + off); off += (size_t)D_IN * D_SAE * sizeof(_Float16);

  sae_init_out<<<(B_SZ * D_SAE + 255) / 256, 256, 0, stream>>>(out);
  sae_split_A<<<(NROWS * D_IN / 8 + 255) / 256, 256, 0, stream>>>(x, Ah, Al);
  sae_split_B<<<(D_IN * D_SAE / 8 + 255) / 256, 256, 0, stream>>>(W_enc, Bh, Bl);
  sae_gemm_mfma<<<dim3(D_SAE / 128, NROWS / 128), 512, 0, stream>>>(
      Ah, Al, Bh, Bl, b_enc, pre);
  sae_top128<<<NROWS, 256, 0, stream>>>(pre, t128i, t128v);
  sae_recur<<<B_SZ, 256, 0, stream>>>(pre, t128i, t128v, gate_raw, zidx, zval);
  sae_decode<<<NROWS, 256, 0, stream>>>(x, W_dec, b_dec, zidx, zval, out);
  sae_scatter_last<<<8, 256, 0, stream>>>(zidx, zval, out);
}

// Round 7
// 653.316 us; speedup vs baseline: 1.1386x; 1.1386x over previous
//
#include <hip/hip_runtime.h>
#include <hip/hip_bf16.h>
#include <math.h>

#define D_IN   768
#define D_SAE  12288
#define T_LEN  64
#define K_TOP  64
#define B_SZ   32
#define NROWS  (B_SZ * T_LEN)   // 2048
#define KT     24               // 768/32 k-tiles

typedef _Float16 h8 __attribute__((ext_vector_type(8)));
typedef float f4 __attribute__((ext_vector_type(4)));

// ---------- helpers ----------
__device__ __forceinline__ unsigned int f2key(float f) {
  unsigned int u = __float_as_uint(f);
  return (u & 0x80000000u) ? ~u : (u | 0x80000000u);
}

// raw barrier: order LDS ops, do NOT drain vmcnt (keep global loads/stores in flight)
__device__ __forceinline__ void barL() {
  __builtin_amdgcn_sched_barrier(0);
  asm volatile("s_waitcnt lgkmcnt(0)" ::: "memory");
  __builtin_amdgcn_s_barrier();
  __builtin_amdgcn_sched_barrier(0);
}

#define GLOAD16(g, l)                                                        \
  __builtin_amdgcn_global_load_lds(                                          \
      (const __attribute__((address_space(1))) unsigned int*)(g),            \
      (__attribute__((address_space(3))) unsigned int*)(l), 16, 0, 0)

// ---------- kernel 0: init output (loss slot + z_last region) ----------
__global__ void sae_init_out(float* __restrict__ d_out) {
  int i = blockIdx.x * blockDim.x + threadIdx.x;
  if (i == 0) d_out[0] = 0.0f;
  if (i < B_SZ * D_SAE) d_out[1 + (size_t)NROWS * D_IN + i] = 0.0f;
}

// ---------- split kernels: fp32 -> (hi, lo*4096) fp16, MFMA-fragment packed ----------
__global__ __launch_bounds__(256) void sae_split_A(
    const float* __restrict__ A, _Float16* __restrict__ Ah, _Float16* __restrict__ Al) {
  int g = blockIdx.x * 256 + threadIdx.x;          // < 128*24*64 = 196608
  int tile = g >> 6, l = g & 63;
  int tm = tile / KT, tk = tile - tm * KT;
  int m = (tm << 4) + (l & 15);
  int k = (tk << 5) + ((l >> 4) << 3);
  const float* src = A + (size_t)m * D_IN + k;
  float4 v0 = *(const float4*)src;
  float4 v1 = *(const float4*)(src + 4);
  float f[8] = {v0.x, v0.y, v0.z, v0.w, v1.x, v1.y, v1.z, v1.w};
  h8 hi, lo;
#pragma unroll
  for (int j = 0; j < 8; ++j) {
    _Float16 h = (_Float16)f[j];
    hi[j] = h;
    lo[j] = (_Float16)((f[j] - (float)h) * 4096.0f);
  }
  *(h8*)(Ah + (size_t)g * 8) = hi;
  *(h8*)(Al + (size_t)g * 8) = lo;
}

__global__ __launch_bounds__(256) void sae_split_B(
    const float* __restrict__ B, _Float16* __restrict__ Bh, _Float16* __restrict__ Bl) {
  int g = blockIdx.x * 256 + threadIdx.x;          // < 768*24*64 = 1179648
  int tile = g >> 6, l = g & 63;
  int tn = tile / KT, tk = tile - tn * KT;
  int n = (tn << 4) + (l & 15);
  int k = (tk << 5) + ((l >> 4) << 3);
  h8 hi, lo;
#pragma unroll
  for (int j = 0; j < 8; ++j) {
    float f = B[(size_t)(k + j) * D_SAE + n];
    _Float16 h = (_Float16)f;
    hi[j] = h;
    lo[j] = (_Float16)((f - (float)h) * 4096.0f);
  }
  *(h8*)(Bh + (size_t)g * 8) = hi;
  *(h8*)(Bl + (size_t)g * 8) = lo;
}

// ---------- kernel 1: encoder GEMM via fp16-split MFMA ----------
__global__ __launch_bounds__(512) void sae_gemm_mfma(
    const _Float16* __restrict__ Ah, const _Float16* __restrict__ Al,
    const _Float16* __restrict__ Bh, const _Float16* __restrict__ Bl,
    const float* __restrict__ bias, float* __restrict__ C) {
  __shared__ _Float16 lds[2][16384];               // 2 x 32 KB
  const int tid = threadIdx.x;
  const int w = tid >> 6, lane = tid & 63;
  const int wm = w >> 2, wn = w & 3;
  const int bmT = blockIdx.y * 8;
  const int bnT = blockIdx.x * 8;

  f4 accm[4][2], accc[4][2];
#pragma unroll
  for (int i = 0; i < 4; ++i)
#pragma unroll
    for (int j = 0; j < 2; ++j) {
      accm[i][j] = (f4){0.f, 0.f, 0.f, 0.f};
      accc[i][j] = (f4){0.f, 0.f, 0.f, 0.f};
    }

#define STAGE(buf, tk)                                                         \
  {                                                                            \
    const _Float16* s0 = Ah + ((size_t)(bmT + w) * KT + (tk)) * 512;           \
    const _Float16* s1 = Al + ((size_t)(bmT + w) * KT + (tk)) * 512;           \
    const _Float16* s2 = Bh + ((size_t)(bnT + w) * KT + (tk)) * 512;           \
    const _Float16* s3 = Bl + ((size_t)(bnT + w) * KT + (tk)) * 512;           \
    GLOAD16(s0 + lane * 8, &lds[buf][(0 * 8 + w) * 512]);                      \
    GLOAD16(s1 + lane * 8, &lds[buf][(1 * 8 + w) * 512]);                      \
    GLOAD16(s2 + lane * 8, &lds[buf][(2 * 8 + w) * 512]);                      \
    GLOAD16(s3 + lane * 8, &lds[buf][(3 * 8 + w) * 512]);                      \
  }

  STAGE(0, 0);
  __syncthreads();
  for (int tk = 0; tk < KT; ++tk) {
    int buf = tk & 1;
    if (tk + 1 < KT) STAGE(buf ^ 1, tk + 1);
    h8 ah[4], al4[4], bh2[2], bl2[2];
#pragma unroll
    for (int i = 0; i < 4; ++i) {
      ah[i]  = *(const h8*)&lds[buf][(wm * 4 + i) * 512 + lane * 8];
      al4[i] = *(const h8*)&lds[buf][4096 + (wm * 4 + i) * 512 + lane * 8];
    }
#pragma unroll
    for (int j = 0; j < 2; ++j) {
      bh2[j] = *(const h8*)&lds[buf][8192 + (wn * 2 + j) * 512 + lane * 8];
      bl2[j] = *(const h8*)&lds[buf][12288 + (wn * 2 + j) * 512 + lane * 8];
    }
#pragma unroll
    for (int i = 0; i < 4; ++i)
#pragma unroll
      for (int j = 0; j < 2; ++j) {
        accm[i][j] = __builtin_amdgcn_mfma_f32_16x16x32_f16(ah[i], bh2[j], accm[i][j], 0, 0, 0);
        accc[i][j] = __builtin_amdgcn_mfma_f32_16x16x32_f16(ah[i], bl2[j], accc[i][j], 0, 0, 0);
        accc[i][j] = __builtin_amdgcn_mfma_f32_16x16x32_f16(al4[i], bh2[j], accc[i][j], 0, 0, 0);
      }
    __syncthreads();
  }
#undef STAGE

  const float kLo = 1.0f / 4096.0f;
  const int colb = blockIdx.x * 128 + wn * 32;
  const int rowb = blockIdx.y * 128 + wm * 64;
#pragma unroll
  for (int j = 0; j < 2; ++j) {
    int col = colb + j * 16 + (lane & 15);
    float bv = bias[col];
#pragma unroll
    for (int i = 0; i < 4; ++i) {
      int row = rowb + i * 16 + ((lane >> 4) << 2);
#pragma unroll
      for (int r = 0; r < 4; ++r)
        C[(size_t)(row + r) * D_SAE + col] = accm[i][j][r] + accc[i][j][r] * kLo + bv;
    }
  }
}

// ---------- kernel 2: exact top-128 per row (radix select) ----------
__global__ __launch_bounds__(256) void sae_top128(
    const float* __restrict__ pre, int* __restrict__ t128i, float* __restrict__ t128v) {
  const int row = blockIdx.x;
  const int tid = threadIdx.x;
  __shared__ unsigned int keys[D_SAE];
  __shared__ int hist[256];
  __shared__ int scn[256];
  __shared__ int sb, srem, scnt, scnt2;
  const float* p = pre + (size_t)row * D_SAE;
  for (int i = tid; i < D_SAE; i += 256) keys[i] = f2key(p[i]);

  const unsigned int PMASK[4] = {0u, 0xFF000000u, 0xFFFF0000u, 0xFFFFFF00u};
  unsigned int pacc = 0;
  int remaining = 128;

  for (int round = 0; round < 4; ++round) {
    const int shift = 24 - 8 * round;
    hist[tid] = 0;
    __syncthreads();
    unsigned int pm = PMASK[round];
    for (int i = tid; i < D_SAE; i += 256) {
      unsigned int k = keys[i];
      if ((k & pm) == pacc) atomicAdd(&hist[(k >> shift) & 255], 1);
    }
    __syncthreads();
    scn[tid] = hist[tid];
    __syncthreads();
    for (int d = 1; d < 256; d <<= 1) {
      int nv = scn[tid] + ((tid + d < 256) ? scn[tid + d] : 0);
      __syncthreads();
      scn[tid] = nv;
      __syncthreads();
    }
    int cum = scn[tid];
    int nxt = (tid < 255) ? scn[tid + 1] : 0;
    if (cum >= remaining && nxt < remaining) { sb = tid; srem = remaining - nxt; }
    __syncthreads();
    pacc |= ((unsigned int)sb) << shift;
    remaining = srem;
    __syncthreads();
  }
  if (tid == 0) { scnt = 0; scnt2 = 0; }
  __syncthreads();
  const int ngt = 128 - remaining;
  for (int i = tid; i < D_SAE; i += 256) {
    unsigned int k = keys[i];
    if (k > pacc) {
      int pos = atomicAdd(&scnt, 1);
      t128i[row * 128 + pos] = i;
      t128v[row * 128 + pos] = p[i];
    } else if (k == pacc) {
      int pos = atomicAdd(&scnt2, 1);
      if (pos < remaining) {
        t128i[row * 128 + ngt + pos] = i;
        t128v[row * 128 + ngt + pos] = p[i];
      }
    }
  }
}

// ---------- kernel 3: recurrence — double-buffered row DMA, counted vmcnt ----------
// 3 barriers/step. wave3 DMAs row t+2 into prerow[t&1] and waits vmcnt(48),
// guaranteeing row t+1 (issued one full step earlier) has landed.
__global__ __launch_bounds__(256) void sae_recur(
    const float* __restrict__ pre, const int* __restrict__ t128i,
    const float* __restrict__ t128v, const float* __restrict__ gate_raw,
    int* __restrict__ zi, float* __restrict__ zv) {
  const int b = blockIdx.x;
  const int tid = threadIdx.x;
  const int lane = tid & 63;
  const int w = tid >> 6;
  __shared__ float prerow[2][D_SAE];                  // 96 KB
  __shared__ float boost[D_SAE];                      // 48 KB
  __shared__ unsigned char mark[D_SAE];               // 12 KB
  __shared__ __align__(16) unsigned long long ckey[192];
  __shared__ int   szi[64];
  __shared__ float szv[64];
  __shared__ float szg[64];                           // z * sigmoid(gate) per slot
  __shared__ int   sne;

  for (int i = tid; i < D_SAE; i += 256) {
    boost[i] = 0.0f;
    mark[i] = 0xFFu;
  }
  if (tid < 64) { szi[tid] = tid; szv[tid] = 0.0f; szg[tid] = 0.0f; }
  // sync-stage row 0 into buf 0 (3072 float4 over 256 threads)
  {
    const float4* src = (const float4*)(pre + (size_t)(b * T_LEN) * D_SAE);
#pragma unroll
    for (int i = 0; i < 12; ++i) {
      float4 v = src[i * 256 + tid];
      *(float4*)&prerow[0][(size_t)(i * 256 + tid) * 4] = v;
    }
  }
  // DMA row 1 into buf 1 (completion enforced at end of step 0 via vmcnt(48))
  if (w == 3) {
    const float* src1 = pre + (size_t)(b * T_LEN + 1) * D_SAE + lane * 4;
#pragma unroll
    for (int i = 0; i < 48; ++i)
      GLOAD16(src1 + i * 256, &prerow[1][i * 256]);
  }
  int ri = 0; float rv = 0.0f;
  if (tid < 128) {
    ri = t128i[(size_t)(b * T_LEN) * 128 + tid];
    rv = t128v[(size_t)(b * T_LEN) * 128 + tid];
  }
  barL();

  const unsigned long long lt64 = (1ull << lane) - 1ull;
  int zidx = 0; float zval = 0.0f, gz = 0.0f, pv = 0.0f;
  int oz = 0;

  for (int t = 0; t < T_LEN; ++t) {
    const int row = b * T_LEN + t;
    const int dbuf = t & 1;
    // ---- A: load state; scatter boost; mark current top-128 ----
    if (w == 0) {
      zidx = szi[lane]; zval = szv[lane]; gz = szg[lane];
      if (zval > 0.0f) boost[zidx] = gz;
      pv = prerow[dbuf][zidx];
    }
    if (w == 3) oz = szi[lane];          // capture old state for boost clear
    if (tid < 128) mark[ri] = (unsigned char)t;
    barL();
    // ---- B: boost gather + key build; wave0 handles extras/pad/ne ----
    unsigned long long kc = 0;
    float myv = 0.0f; int myi = 0;
    if (tid < 128) {
      myi = ri;
      myv = rv + boost[ri];
      kc = (((unsigned long long)f2key(myv)) << 14) | (unsigned)(16383 - myi);
      ckey[tid] = kc;
    }
    if (w == 0) {
      bool active = (zval > 0.0f);
      bool matched = active && (mark[zidx] == (unsigned char)t);
      bool extra = active && !matched;
      unsigned long long em = __ballot(extra);
      int ne = __popcll(em);
      if (extra) {
        int pos = __popcll(em & lt64);
        float v = pv + gz;
        ckey[128 + pos] =
            (((unsigned long long)f2key(v)) << 14) | (unsigned)(16383 - zidx);
      }
      if (lane == ne) {   // single -INF pad (covers odd-nk pair read)
        ckey[128 + ne] = (((unsigned long long)f2key(-INFINITY)) << 14) |
                         (unsigned)(16383 - (D_SAE + ne));
      }
      if (lane == 0) sne = ne;
    }
    barL();
    // ---- CD: DMA row t+2 (wave3) + t128 prefetch + rank + select ----
    const int nk = 128 + sne;
    int nri = ri; float nrv = rv;
    if (tid < 128 && t + 1 < T_LEN) {
      nri = t128i[(size_t)(row + 1) * 128 + tid];
      nrv = t128v[(size_t)(row + 1) * 128 + tid];
    }
    if (w == 3) {
      const int last = b * T_LEN + T_LEN - 1;
      const int nrow = (row + 2 <= last) ? row + 2 : last;
      const float* src = pre + (size_t)nrow * D_SAE + lane * 4;
      float* dst = &prerow[dbuf][0];
#pragma unroll
      for (int i = 0; i < 48; ++i)
        GLOAD16(src + i * 256, dst + i * 256);
      boost[oz] = 0.0f;
      __builtin_amdgcn_sched_barrier(0);
      asm volatile("s_waitcnt vmcnt(48)" ::: "memory");  // row t+1 batch retired
      __builtin_amdgcn_sched_barrier(0);
    }
    if (tid >= 128 && tid < nk) {
      kc = ckey[tid];
      myi = 16383 - (int)(kc & 0x3FFFu);
      unsigned int hv = (unsigned int)(kc >> 14);
      myv = (hv & 0x80000000u) ? __uint_as_float(hv & 0x7FFFFFFFu)
                               : __uint_as_float(~hv);
    }
    int r = 0;
    if (tid < nk) {
      const int np = (nk + 1) >> 1;
#pragma unroll 8
      for (int j = 0; j < np; ++j) {
        ulonglong2 kk = *(const ulonglong2*)&ckey[2 * j];
        r += (int)(kk.x > kc) + (int)(kk.y > kc);
      }
      if (r < K_TOP) {   // rank IS the position
        float rl = fmaxf(myv, 0.0f);
        float g = gate_raw[myi];
        float s = 1.0f / (1.0f + __expf(-g));
        szi[r] = myi;
        szv[r] = rl;
        szg[r] = rl * s;                 // 0 when rl==0 (s finite)
        zi[(size_t)row * 64 + r] = myi;  // fire-and-forget global stores
        zv[(size_t)row * 64 + r] = rl;
      }
    }
    barL();
    ri = nri; rv = nrv;
  }
}

// ---------- kernel 4: sparse decoder + recon loss ----------
__global__ __launch_bounds__(256) void sae_decode(
    const float* __restrict__ x, const float* __restrict__ W_dec,
    const float* __restrict__ b_dec, const int* __restrict__ zi,
    const float* __restrict__ zv, float* __restrict__ d_out) {
  const int row = blockIdx.x;
  const int tid = threadIdx.x;
  __shared__ int   si[64];
  __shared__ float sv[64];
  __shared__ float red[4];
  if (tid < 64) { si[tid] = zi[row * 64 + tid]; sv[tid] = zv[row * 64 + tid]; }
  __syncthreads();
  float a0 = b_dec[tid], a1 = b_dec[tid + 256], a2 = b_dec[tid + 512];
  for (int k = 0; k < 64; ++k) {
    float v = sv[k];
    if (v != 0.0f) {
      const float* wp = W_dec + (size_t)si[k] * D_IN;
      a0 = fmaf(v, wp[tid], a0);
      a1 = fmaf(v, wp[tid + 256], a1);
      a2 = fmaf(v, wp[tid + 512], a2);
    }
  }
  float* xhat = d_out + 1;
  size_t base = (size_t)row * D_IN;
  xhat[base + tid]       = a0;
  xhat[base + tid + 256] = a1;
  xhat[base + tid + 512] = a2;
  float d0 = a0 - x[base + tid];
  float d1 = a1 - x[base + tid + 256];
  float d2 = a2 - x[base + tid + 512];
  float s = d0 * d0 + d1 * d1 + d2 * d2;
  for (int o = 32; o > 0; o >>= 1) s += __shfl_down(s, o);
  if ((tid & 63) == 0) red[tid >> 6] = s;
  __syncthreads();
  if (tid == 0) {
    float tot = red[0] + red[1] + red[2] + red[3];
    atomicAdd(d_out, tot * (1.0f / (float)NROWS));
  }
}

// ---------- kernel 5: scatter z at t = T-1 ----------
__global__ void sae_scatter_last(const int* __restrict__ zi,
                                 const float* __restrict__ zv,
                                 float* __restrict__ d_out) {
  int i = blockIdx.x * blockDim.x + threadIdx.x;
  if (i >= B_SZ * 64) return;
  int b = i >> 6, k = i & 63;
  int row = b * T_LEN + (T_LEN - 1);
  float* zlast = d_out + 1 + (size_t)NROWS * D_IN;
  zlast[(size_t)b * D_SAE + zi[row * 64 + k]] = zv[row * 64 + k];
}

// ---------- launch ----------
extern "C" void kernel_launch(void* const* d_in, const int* in_sizes, int n_in,
                              void* d_out, int out_size, void* d_ws, size_t ws_size,
                              hipStream_t stream) {
  const float* x        = (const float*)d_in[0];
  const float* W_enc    = (const float*)d_in[1];
  const float* W_dec    = (const float*)d_in[2];
  const float* b_enc    = (const float*)d_in[3];
  const float* b_dec    = (const float*)d_in[4];
  const float* gate_raw = (const float*)d_in[5];
  float* out = (float*)d_out;

  char* ws = (char*)d_ws;
  size_t off = 0;
  float* pre   = (float*)(ws + off); off += (size_t)NROWS * D_SAE * sizeof(float);
  int*   t128i = (int*)(ws + off);   off += (size_t)NROWS * 128 * sizeof(int);
  float* t128v = (float*)(ws + off); off += (size_t)NROWS * 128 * sizeof(float);
  int*   zidx  = (int*)(ws + off);   off += (size_t)NROWS * 64 * sizeof(int);
  float* zval  = (float*)(ws + off); off += (size_t)NROWS * 64 * sizeof(float);
  _Float16* Ah = (_Float16*)(ws + off); off += (size_t)NROWS * D_IN * sizeof(_Float16);
  _Float16* Al = (_Float16*)(ws + off); off += (size_t)NROWS * D_IN * sizeof(_Float16);
  _Float16* Bh = (_Float16*)(ws + off); off += (size_t)D_IN * D_SAE * sizeof(_Float16);
  _Float16* Bl = (_Float16*)(ws + off); off += (size_t)D_IN * D_SAE * sizeof(_Float16);

  sae_init_out<<<(B_SZ * D_SAE + 255) / 256, 256, 0, stream>>>(out);
  sae_split_A<<<(NROWS * D_IN / 8 + 255) / 256, 256, 0, stream>>>(x, Ah, Al);
  sae_split_B<<<(D_IN * D_SAE / 8 + 255) / 256, 256, 0, stream>>>(W_enc, Bh, Bl);
  sae_gemm_mfma<<<dim3(D_SAE / 128, NROWS / 128), 512, 0, stream>>>(
      Ah, Al, Bh, Bl, b_enc, pre);
  sae_top128<<<NROWS, 256, 0, stream>>>(pre, t128i, t128v);
  sae_recur<<<B_SZ, 256, 0, stream>>>(pre, t128i, t128v, gate_raw, zidx, zval);
  sae_decode<<<NROWS, 256, 0, stream>>>(x, W_dec, b_dec, zidx, zval, out);
  sae_scatter_last<<<8, 256, 0, stream>>>(zidx, zval, out);
}